// Round 7
// baseline (292.549 us; speedup 1.0000x reference)
//
#include <hip/hip_runtime.h>

// Pillar scatter, gather-formulated with per-row binning:
//   out[b, f, y, x] = sum of pillars[b,p,:] over active pillars p at (y,x).
// Output [4, 64, 512, 512] fp32 (268 MB), written exactly once (no memset).
//
// Pass 1 (bin): active pillars -> per-(b,y) row lists.
// Pass 2 (fill): block = (b, 16-feature group, 4-row y group). Stages only its
//   16 features of the 4 rows' pillars in LDS, builds per-row x->slot maps via
//   LDS CAS (duplicates merged in LDS), then emits 8 KB CONTIGUOUS per plane
//   (4 consecutive y rows x 512 x) with dense nontemporal float4 stores.
//   R4/R6 wrote 2 KB chunks at 1 MB stride -> effective ~4.7 TB/s; larger
//   contiguous chunks target the 6.3 TB/s fill ceiling.
// Pass 3 (fixup): atomicAdd the (normally zero) row-overflow entries.

#define NF 64
#define XS 512
#define YS 512
#define ROWCAP 64            // max pillars per (b,y) row; mean ~12
#define PST 20               // floats per staged pillar (16 + pad), 80B, 16B-aligned
#define YBLK 4
#define FBLK 16
#define OVCAP 16384

typedef float vf4 __attribute__((ext_vector_type(4)));

__global__ void __launch_bounds__(256) bin_pillars(
    const int* __restrict__ coord,
    const int* __restrict__ contains,
    int* __restrict__ rowcnt,
    int* __restrict__ rowlist,
    int* __restrict__ ovcnt,
    int* __restrict__ ovlist,
    int BP, int P) {
  int gid = blockIdx.x * 256 + threadIdx.x;
  if (gid >= BP) return;
  if (contains[gid] == 0) return;
  int y = coord[gid * 3 + 1];
  int x = coord[gid * 3 + 2];
  int b = gid / P;
  int by = (b << 9) | y;
  int k = atomicAdd(rowcnt + by, 1);
  if (k < ROWCAP) {
    rowlist[by * ROWCAP + k] = (x << 16) | gid;   // gid < 48000 fits 16 bits
  } else {
    int o = atomicAdd(ovcnt, 1);
    if (o < OVCAP) ovlist[o] = gid;
  }
}

__global__ void __launch_bounds__(256) fill_out(
    const float* __restrict__ pillars,
    const int* __restrict__ rowcnt,
    const int* __restrict__ rowlist,
    float* __restrict__ out) {
  // bid: [b | fg | yg] with yg fastest -> consecutive blocks write adjacent
  // 8 KB segments of the same 16 planes.
  int bid = blockIdx.x;
  int yg = bid & 127;
  int fg = (bid >> 7) & 3;
  int b  = bid >> 9;
  int y0 = yg << 2;           // YBLK rows
  int f0 = fg << 4;           // FBLK features
  int by0 = (b << 9) | y0;

  __shared__ int xmap[YBLK * XS];               // 8 KB: row k -> x -> slot
  __shared__ float prow[YBLK * ROWCAP * PST];   // 20 KB staged features

  int t = threadIdx.x;
#pragma unroll
  for (int i = 0; i < 8; ++i) xmap[t + 256 * i] = -1;
  __syncthreads();

  int n[YBLK];
#pragma unroll
  for (int k = 0; k < YBLK; ++k) {
    int c = rowcnt[by0 + k];
    n[k] = c > ROWCAP ? ROWCAP : c;
  }

  // claim cells: thread -> (row kc = t>>6, slot sc = t&63)
  int kc = t >> 6, sc = t & 63;
  int myold = -1;
  if (sc < n[kc]) {
    int e = rowlist[(by0 + kc) * ROWCAP + sc];
    int x = e >> 16;
    myold = atomicCAS(&xmap[(kc << 9) + x], -1, sc);
  }
  __syncthreads();

  // stage 16 features of each listed pillar: thread -> (slot ss, quarter q)
  int ss = t >> 2, q = t & 3;
#pragma unroll
  for (int k = 0; k < YBLK; ++k) {
    if (ss < n[k]) {
      int g = rowlist[(by0 + k) * ROWCAP + ss] & 0xFFFF;
      vf4 v = *(const vf4*)&pillars[((size_t)g << 6) + f0 + (q << 2)];
      *(vf4*)&prow[((k << 6) + ss) * PST + (q << 2)] = v;
    }
  }
  __syncthreads();

  // merge duplicate-cell losers into the winner's staged row (rare)
  if (myold >= 0) {
    int wbase = ((kc << 6) + myold) * PST;
    int mbase = ((kc << 6) + sc) * PST;
    for (int f = 0; f < FBLK; ++f)
      atomicAdd(&prow[wbase + f], prow[mbase + f]);
  }
  __syncthreads();

  // emit: phase = t>>7 covers rows {2*phase, 2*phase+1}; x4 = (t&127)*4.
  // Per fl iteration the block writes one full 8 KB contiguous plane segment.
  int phase = t >> 7;
  int x4 = (t & 127) << 2;
  int  o[2][4];
  bool m[2][4];
#pragma unroll
  for (int jj = 0; jj < 2; ++jj) {
    int k = (phase << 1) + jj;
    int4 s4 = *(const int4*)&xmap[(k << 9) + x4];
    m[jj][0] = s4.x >= 0; o[jj][0] = ((k << 6) + (m[jj][0] ? s4.x : 0)) * PST;
    m[jj][1] = s4.y >= 0; o[jj][1] = ((k << 6) + (m[jj][1] ? s4.y : 0)) * PST;
    m[jj][2] = s4.z >= 0; o[jj][2] = ((k << 6) + (m[jj][2] ? s4.z : 0)) * PST;
    m[jj][3] = s4.w >= 0; o[jj][3] = ((k << 6) + (m[jj][3] ? s4.w : 0)) * PST;
  }
  size_t base0 = (((size_t)(b * NF + f0)) << 18) + (size_t)x4;
#pragma unroll
  for (int fl = 0; fl < FBLK; ++fl) {
#pragma unroll
    for (int jj = 0; jj < 2; ++jj) {
      int yy = y0 + (phase << 1) + jj;
      vf4 v;
      v.x = m[jj][0] ? prow[o[jj][0] + fl] : 0.f;
      v.y = m[jj][1] ? prow[o[jj][1] + fl] : 0.f;
      v.z = m[jj][2] ? prow[o[jj][2] + fl] : 0.f;
      v.w = m[jj][3] ? prow[o[jj][3] + fl] : 0.f;
      __builtin_nontemporal_store(
          v, (vf4*)(out + base0 + ((size_t)fl << 18) + ((size_t)yy << 9)));
    }
  }
}

__global__ void __launch_bounds__(256) fixup_overflow(
    const float* __restrict__ pillars,
    const int* __restrict__ coord,
    const int* __restrict__ ovlist,
    const int* __restrict__ ovcnt,
    float* __restrict__ out,
    int P) {
  int gid = blockIdx.x * 256 + threadIdx.x;
  int w = gid >> 6;
  int lane = gid & 63;
  int n = *ovcnt;
  if (n > OVCAP) n = OVCAP;
  int nw = gridDim.x * 4;
  for (int i = w; i < n; i += nw) {
    int g = ovlist[i];
    int y = coord[g * 3 + 1];
    int x = coord[g * 3 + 2];
    int b = g / P;
    atomicAdd(out + (((size_t)(b * NF + lane)) << 18) + ((size_t)y << 9) + x,
              pillars[((size_t)g << 6) + lane]);
  }
}

extern "C" void kernel_launch(void* const* d_in, const int* in_sizes, int n_in,
                              void* d_out, int out_size, void* d_ws, size_t ws_size,
                              hipStream_t stream) {
  const float* pillars  = (const float*)d_in[0];
  const int*   coord    = (const int*)d_in[1];
  const int*   contains = (const int*)d_in[2];
  float* out = (float*)d_out;

  const int BP = in_sizes[2];                    // B * P = 48000
  const int B  = out_size / (NF * XS * YS);      // 4
  const int P  = BP / B;                         // 12000
  const int NROW = B * YS;                       // 2048

  // workspace layout: [rowcnt 2048 ints][ovcnt 1 int + pad][rowlist][ovlist]
  int* rowcnt  = (int*)d_ws;
  int* ovcnt   = rowcnt + NROW;
  int* rowlist = ovcnt + 4;
  int* ovlist  = rowlist + NROW * ROWCAP;

  (void)hipMemsetAsync(rowcnt, 0, (size_t)(NROW + 4) * sizeof(int), stream);

  bin_pillars<<<(BP + 255) / 256, 256, 0, stream>>>(coord, contains, rowcnt,
                                                    rowlist, ovcnt, ovlist, BP, P);
  // B * (YS/YBLK) * (NF/FBLK) = B * 128 * 4 blocks
  fill_out<<<B * 512, 256, 0, stream>>>(pillars, rowcnt, rowlist, out);
  fixup_overflow<<<64, 256, 0, stream>>>(pillars, coord, ovlist, ovcnt, out, P);
}